// Round 15
// baseline (1182.239 us; speedup 1.0000x reference)
//
#include <hip/hip_runtime.h>
#include <stdint.h>
#include <stddef.h>

#define FT_IN 41024
#define KHALF 256
#define BATCH 8192
#define NMACRO 160        // 160 x 256-K macros + one 64-K leftover (641*64 = 41024)

typedef __attribute__((ext_vector_type(8))) short short8;
typedef __attribute__((ext_vector_type(4))) short short4v;
typedef __attribute__((ext_vector_type(4))) float f32x4;
typedef __attribute__((ext_vector_type(2))) uint32_t u32x2;
typedef __attribute__((ext_vector_type(4))) _Float16 half4v;

typedef const __attribute__((address_space(1))) uint32_t* gas1_t;
typedef __attribute__((address_space(3))) uint32_t* las3_t;

__device__ __forceinline__ unsigned short f2bf(float f) {
  union { float f; uint32_t u; } x; x.f = f;
  uint32_t u = x.u + 0x7FFFu + ((x.u >> 16) & 1u);
  return (unsigned short)(u >> 16);
}

#define MFMA16(acc, a, b) \
  asm("v_mfma_f32_16x16x32_bf16 %0, %1, %2, %0" : "+v"(acc) : "v"(a), "v"(b))

#define CVTPK(dst, lo, hi) \
  asm("v_cvt_pk_bf16_f32 %0, %1, %2" : "=v"(dst) : "v"(lo), "v"(hi))

// ---------------- kernel 1: ft_w fp32 -> bf16 ----------------
__global__ void wprep_kernel(const float* __restrict__ w,
                             unsigned short* __restrict__ o, int n4) {
  int i = blockIdx.x * blockDim.x + threadIdx.x;
  int stride = gridDim.x * blockDim.x;
  for (; i < n4; i += stride) {
    f32x4 v = ((const f32x4*)w)[i];
    short4v b;
    b.x = (short)f2bf(v.x); b.y = (short)f2bf(v.y);
    b.z = (short)f2bf(v.z); b.w = (short)f2bf(v.w);
    ((short4v*)o)[i] = b;
  }
}

// ---------------- kernel 2: feature-transform GEMM ----------------
// grid: 256 rowblocks x 2 sets = 512 WGs (2/CU); block 256 (4 waves).
// per-WG tile: 32 rows x 256 cols x FULL K (no K-split -> no partials).
// K processed in 256-wide macros: A staged 1 KB/row/macro (fp32 -> cvt ->
// sA bf16 [32][512B], XOR-swizzled); W (bf16, pre-converted) per 64-K sub,
// glds double-buffered — glds only issued after a full __syncthreads into
// the non-read buffer (R4-proven pattern). One raw s_barrier per macro
// before the sA overwrite. Epilogue: +ftb, clip01, fp16 ft out.
__global__ __launch_bounds__(256, 2) void ftgemm_kernel(
    const float* __restrict__ f1g, const float* __restrict__ f2g,
    const unsigned short* __restrict__ wb,
    const float* __restrict__ ftbv,
    _Float16* __restrict__ ftout) {
  __shared__ alignas(16) char sA[16384];       // 32 rows x 512 B
  __shared__ alignas(16) char sW[2][32768];    // 256 cols x 128 B, dbuf

  const int nwg = (int)gridDim.x;              // 512, divisible by 8
  const int orig = (int)blockIdx.x;
  int bid = (orig & 7) * (nwg >> 3) + (orig >> 3);
  const int rb = bid & 255;
  const int st = bid >> 8;

  const int tid  = (int)threadIdx.x;
  const int lane = tid & 63;
  const int wv   = tid >> 6;         // 0..3
  const int wc   = wv << 6;          // wave col offset 0/64/128/192
  const int r16  = lane & 15;
  const int hi   = lane >> 4;

  const float* F = (st ? f2g : f1g) + (size_t)rb * (32ull * FT_IN);

  // A macro staging: thread -> row (tid>>3), 32 contiguous floats at
  // chunk (tid&7)*32. 8 threads x 128 B = 1 KB burst per row.
  const int arow = tid >> 3;         // 0..31
  const int achk = tid & 7;
  const float* aptr = F + (size_t)arow * FT_IN + achk * 32;

  // W staging (identical to proven map): chunk c = i*256+tid covers
  // wcol = c>>3 (i adds 32), kc = c&7; source XOR-pre-swizzled.
  const int wrow = tid >> 3;
  const int wkc  = tid & 7;
  const int wkcs = wkc ^ (wrow & 7);
  const unsigned short* wptr = wb + (size_t)wrow * FT_IN;

  // ftb for this thread's 4 output col positions
  float fb[4];
  #pragma unroll
  for (int n = 0; n < 4; ++n) fb[n] = ftbv[wc + n * 16 + r16];

  f32x4 areg[8];
  f32x4 acc[2][4];
  const f32x4 fzero = {0.f, 0.f, 0.f, 0.f};
  #pragma unroll
  for (int m = 0; m < 2; ++m)
    #pragma unroll
    for (int n = 0; n < 4; ++n) acc[m][n] = fzero;

  // prologue: A macro 0 + W sub 0
  #pragma unroll
  for (int i = 0; i < 8; ++i)
    areg[i] = *(const f32x4*)(aptr + i * 4);
  #pragma unroll
  for (int i = 0; i < 8; ++i) {
    const unsigned short* g = wptr + (size_t)i * (32ull * FT_IN) + wkcs * 8;
    __builtin_amdgcn_global_load_lds((gas1_t)g,
        (las3_t)&sW[0][(i * 256 + tid) * 16], 16, 0, 0);
  }

  const int xr = (arow & 7) << 4;              // sA row XOR
  const int swz = (r16 & 7) << 4;              // read-side XOR
  int buf = 0;

  for (int mt = 0; mt <= NMACRO; ++mt) {
    const bool lastm = (mt == NMACRO);
    // phase A: cvt + store A(mt) into sA (row stride 512 B, byte ^ xr)
    if (!lastm) {
      #pragma unroll
      for (int i = 0; i < 8; ++i) {            // chunk i: 4 floats -> 8 B
        f32x4 v = areg[i];
        uint32_t b0, b1;
        CVTPK(b0, v.x, v.y);
        CVTPK(b1, v.z, v.w);
        u32x2 b; b.x = b0; b.y = b1;
        *(u32x2*)(sA + arow * 512 + ((achk * 64 + i * 8) ^ xr)) = b;
      }
    } else {
      #pragma unroll
      for (int i = 0; i < 2; ++i) {            // leftover: 8 floats
        f32x4 v = areg[i];
        uint32_t b0, b1;
        CVTPK(b0, v.x, v.y);
        CVTPK(b1, v.z, v.w);
        u32x2 b; b.x = b0; b.y = b1;
        *(u32x2*)(sA + arow * 512 + ((achk * 16 + i * 8) ^ xr)) = b;
      }
    }
    const int nsub = lastm ? 1 : 4;
    for (int s2 = 0; s2 < nsub; ++s2) {
      // entry sync: drains glds for W(gs) issued one sub ago; sA visible
      __syncthreads();
      const int gs = mt * 4 + s2;
      if (gs < 640) {                          // stage W(gs+1) into buf^1
        const unsigned short* wp = wptr + (size_t)(gs + 1) * 64;
        #pragma unroll
        for (int i = 0; i < 8; ++i) {
          const unsigned short* g = wp + (size_t)i * (32ull * FT_IN) + wkcs * 8;
          __builtin_amdgcn_global_load_lds((gas1_t)g,
              (las3_t)&sW[buf ^ 1][(i * 256 + tid) * 16], 16, 0, 0);
        }
      }
      if (!lastm && s2 == 3) {                 // prefetch A(mt+1)
        if (mt + 1 < NMACRO) {
          const float* ap = aptr + (size_t)(mt + 1) * 256;
          #pragma unroll
          for (int i = 0; i < 8; ++i)
            areg[i] = *(const f32x4*)(ap + i * 4);
        } else {                               // leftover: 8 floats at achk*8
          const float* ap = F + (size_t)arow * FT_IN + NMACRO * 256 + achk * 8;
          areg[0] = *(const f32x4*)(ap);
          areg[1] = *(const f32x4*)(ap + 4);
        }
      }
      // MFMA over sA sub-slice s2 x sW[buf]
      const char* sWb = sW[buf];
      #pragma unroll
      for (int k2 = 0; k2 < 2; ++k2) {
        const int koA = (s2 * 128 + k2 * 64 + hi * 16) ^ swz;
        const int koW = (k2 * 64 + hi * 16) ^ swz;
        short8 av[2], bv[4];
        #pragma unroll
        for (int m = 0; m < 2; ++m)
          av[m] = *(const short8*)(sA + (m * 16 + r16) * 512 + koA);
        #pragma unroll
        for (int n = 0; n < 4; ++n)
          bv[n] = *(const short8*)(sWb + (wc + n * 16 + r16) * 128 + koW);
        #pragma unroll
        for (int m = 0; m < 2; ++m)
          #pragma unroll
          for (int n = 0; n < 4; ++n)
            MFMA16(acc[m][n], av[m], bv[n]);
      }
      buf ^= 1;
    }
    // macro end: raw barrier (no vmcnt drain — A(mt+1)/W glds stay in
    // flight). sA overwrite after raw barrier = R4-proven (ds_write path).
    __builtin_amdgcn_sched_barrier(0);
    __builtin_amdgcn_s_barrier();
    __builtin_amdgcn_sched_barrier(0);
  }

  // epilogue: ft = clip01(acc + ftb), fp16, layout [set*256+col][row]
  _Float16* pb = ftout + (size_t)(st * KHALF) * BATCH;
  const int growb = rb * 32 + hi * 4;
  #pragma unroll
  for (int n = 0; n < 4; ++n) {
    const int gcol = wc + n * 16 + r16;
    #pragma unroll
    for (int m = 0; m < 2; ++m) {
      f32x4 a = acc[m][n];
      half4v h;
      h.x = (_Float16)fminf(fmaxf(a.x + fb[n], 0.f), 1.f);
      h.y = (_Float16)fminf(fmaxf(a.y + fb[n], 0.f), 1.f);
      h.z = (_Float16)fminf(fmaxf(a.z + fb[n], 0.f), 1.f);
      h.w = (_Float16)fminf(fmaxf(a.w + fb[n], 0.f), 1.f);
      *(half4v*)(pb + (size_t)gcol * BATCH + (growb + m * 16)) = h;
    }
  }
}

// ---------------- kernel 3: tail MLP ----------------
// 256 blocks x 32 rows; ft already biased+clipped (fp16, [c][row]).
__global__ __launch_bounds__(256) void tail_kernel(
    const _Float16* __restrict__ ft,
    const float* __restrict__ h1w, const float* __restrict__ h1b,
    const float* __restrict__ h2w, const float* __restrict__ h2b,
    const float* __restrict__ outw, const float* __restrict__ outb,
    float* __restrict__ out) {
  __shared__ float sh1t[512 * 36];
  __shared__ float sh2[32 * 32];
  __shared__ float sow[32];
  __shared__ float sh1b[32];
  __shared__ float sh2b[32];
  __shared__ float sob[1];

  const int tid = (int)threadIdx.x;
  for (int i = tid; i < 512 * 32; i += 256) {
    const int j = i >> 9, c = i & 511;
    sh1t[c * 36 + j] = h1w[i];
  }
  for (int i = tid; i < 1024; i += 256) sh2[i] = h2w[i];
  if (tid < 32) { sow[tid] = outw[tid]; sh1b[tid] = h1b[tid]; sh2b[tid] = h2b[tid]; }
  if (tid == 0) sob[0] = outb[0];
  __syncthreads();

  const int r  = tid & 31;
  const int cg = tid >> 5;
  const int t  = (int)blockIdx.x * 32 + r;

  float a1p[32];
  #pragma unroll
  for (int j = 0; j < 32; ++j) a1p[j] = 0.f;

  for (int ci = 0; ci < 64; ++ci) {
    const int c = cg * 64 + ci;
    float v = (float)ft[(size_t)c * BATCH + t];
    const f32x4* wr4 = (const f32x4*)(sh1t + c * 36);
    #pragma unroll
    for (int q = 0; q < 8; ++q) {
      f32x4 wv = wr4[q];
      a1p[q * 4 + 0] += v * wv.x; a1p[q * 4 + 1] += v * wv.y;
      a1p[q * 4 + 2] += v * wv.z; a1p[q * 4 + 3] += v * wv.w;
    }
  }

  float* red = sh1t;                  // [8][32][33]
  __syncthreads();
  #pragma unroll
  for (int j = 0; j < 32; ++j)
    red[(cg * 32 + r) * 33 + j] = a1p[j];
  __syncthreads();

  if (tid < 32) {
    float a1[32];
    #pragma unroll
    for (int j = 0; j < 32; ++j) a1[j] = sh1b[j];
    for (int g = 0; g < 8; ++g)
      #pragma unroll
      for (int j = 0; j < 32; ++j)
        a1[j] += red[(g * 32 + tid) * 33 + j];
    #pragma unroll
    for (int j = 0; j < 32; ++j) a1[j] = fminf(fmaxf(a1[j], 0.f), 1.f);

    float a2[32];
    #pragma unroll
    for (int j = 0; j < 32; ++j) {
      float x = sh2b[j];
      const f32x4* w2 = (const f32x4*)(sh2 + j * 32);
      #pragma unroll
      for (int q = 0; q < 8; ++q) {
        f32x4 wv = w2[q];
        x += a1[q * 4 + 0] * wv.x + a1[q * 4 + 1] * wv.y +
             a1[q * 4 + 2] * wv.z + a1[q * 4 + 3] * wv.w;
      }
      a2[j] = fminf(fmaxf(x, 0.f), 1.f);
    }
    float o = sob[0];
    #pragma unroll
    for (int j = 0; j < 32; ++j) o += a2[j] * sow[j];
    out[(int)blockIdx.x * 32 + tid] = o;
  }
}

// ---------------- launch ----------------
extern "C" void kernel_launch(void* const* d_in, const int* in_sizes, int n_in,
                              void* d_out, int out_size, void* d_ws, size_t ws_size,
                              hipStream_t stream) {
  const float* f1   = (const float*)d_in[0];
  const float* f2   = (const float*)d_in[1];
  const float* ftw  = (const float*)d_in[2];
  const float* ftb  = (const float*)d_in[3];
  const float* h1w  = (const float*)d_in[4];
  const float* h1b  = (const float*)d_in[5];
  const float* h2w  = (const float*)d_in[6];
  const float* h2b  = (const float*)d_in[7];
  const float* outw = (const float*)d_in[8];
  const float* outb = (const float*)d_in[9];
  float* out = (float*)d_out;

  unsigned short* wb = (unsigned short*)d_ws;
  const size_t woff = (size_t)KHALF * FT_IN * 2;            // 21,004,288 B
  _Float16* ftbuf = (_Float16*)((char*)d_ws + woff);        // 8.4 MB

  wprep_kernel<<<2048, 256, 0, stream>>>(ftw, wb, (KHALF * FT_IN) / 4);
  ftgemm_kernel<<<512, 256, 0, stream>>>(f1, f2, wb, ftb, ftbuf);
  tail_kernel<<<BATCH / 32, 256, 0, stream>>>(ftbuf, h1w, h1b, h2w, h2b,
                                              outw, outb, out);
}

// Round 16
// 1122.563 us; speedup vs baseline: 1.0532x; 1.0532x over previous
//
#include <hip/hip_runtime.h>
#include <stdint.h>
#include <stddef.h>

#define FT_IN 41024
#define KHALF 256
#define BATCH 8192
#define NMACRO 160        // 160 x 256-K macros + one 64-K leftover (641*64)

typedef __attribute__((ext_vector_type(8))) short short8;
typedef __attribute__((ext_vector_type(4))) short short4v;
typedef __attribute__((ext_vector_type(4))) float f32x4;
typedef __attribute__((ext_vector_type(2))) uint32_t u32x2;
typedef __attribute__((ext_vector_type(4))) _Float16 half4v;

typedef const __attribute__((address_space(1))) uint32_t* gas1_t;
typedef __attribute__((address_space(3))) uint32_t* las3_t;

__device__ __forceinline__ unsigned short f2bf(float f) {
  union { float f; uint32_t u; } x; x.f = f;
  uint32_t u = x.u + 0x7FFFu + ((x.u >> 16) & 1u);
  return (unsigned short)(u >> 16);
}

#define MFMA16(acc, a, b) \
  asm("v_mfma_f32_16x16x32_bf16 %0, %1, %2, %0" : "+v"(acc) : "v"(a), "v"(b))

#define CVTPK(dst, lo, hi) \
  asm("v_cvt_pk_bf16_f32 %0, %1, %2" : "=v"(dst) : "v"(lo), "v"(hi))

// ---------------- kernel 1: ft_w fp32 -> bf16 ----------------
__global__ void wprep_kernel(const float* __restrict__ w,
                             unsigned short* __restrict__ o, int n4) {
  int i = blockIdx.x * blockDim.x + threadIdx.x;
  int stride = gridDim.x * blockDim.x;
  for (; i < n4; i += stride) {
    f32x4 v = ((const f32x4*)w)[i];
    short4v b;
    b.x = (short)f2bf(v.x); b.y = (short)f2bf(v.y);
    b.z = (short)f2bf(v.z); b.w = (short)f2bf(v.w);
    ((short4v*)o)[i] = b;
  }
}

// ---------------- kernel 2: feature-transform GEMM ----------------
// grid: 256 rowblocks x 2 sets = 512 WGs (2/CU); block 256 (4 waves).
// per-WG tile: 32 rows x 256 cols x FULL K (no partials). K in 256-wide
// macros (1 KB per row per macro -> DRAM page locality). sA is FOUR
// sub-tiles [4][32 rows][128 B], each using the PROVEN conflict-free
// layout (row stride 128 B, byte ^ (row&7)<<4). A thread-map strided:
// thread (arow,achk) loads f32x4 at achk*4 + j*32 (j=0..7) -> LDS write
// instruction j covers 8 distinct k-units x 2 rows = 2-way max (free).
// W: bf16 glds double-buffered, issued only after __syncthreads into the
// non-read buffer (R4-proven). One raw s_barrier per macro (sA overwrite).
__global__ __launch_bounds__(256, 2) void ftgemm_kernel(
    const float* __restrict__ f1g, const float* __restrict__ f2g,
    const unsigned short* __restrict__ wb,
    const float* __restrict__ ftbv,
    _Float16* __restrict__ ftout) {
  __shared__ alignas(16) char sA[4][4096];     // [sub][32 rows x 128 B]
  __shared__ alignas(16) char sW[2][32768];    // 256 cols x 128 B, dbuf

  const int nwg = (int)gridDim.x;              // 512, divisible by 8
  const int orig = (int)blockIdx.x;
  int bid = (orig & 7) * (nwg >> 3) + (orig >> 3);
  const int rb = bid & 255;
  const int st = bid >> 8;

  const int tid  = (int)threadIdx.x;
  const int lane = tid & 63;
  const int wv   = tid >> 6;         // 0..3
  const int wc   = wv << 6;          // wave col offset 0/64/128/192
  const int r16  = lane & 15;
  const int hi   = lane >> 4;

  const float* F = (st ? f2g : f1g) + (size_t)rb * (32ull * FT_IN);

  // A macro staging (strided map): thread (arow = tid>>3, achk = tid&7);
  // instruction j loads f32x4 at k-float achk*4 + j*32. Per row the 8
  // issued loads cover a contiguous 1 KB (page-friendly).
  const int arow = tid >> 3;         // 0..31
  const int achk = tid & 7;
  const float* aptr = F + (size_t)arow * FT_IN + achk * 4;

  // W staging (proven map): chunk c = i*256+tid -> wcol = c>>3, kc = c&7;
  // source XOR-pre-swizzled.
  const int wrow = tid >> 3;
  const int wkc  = tid & 7;
  const int wkcs = wkc ^ (wrow & 7);
  const unsigned short* wptr = wb + (size_t)wrow * FT_IN;

  float fb[4];
  #pragma unroll
  for (int n = 0; n < 4; ++n) fb[n] = ftbv[wc + n * 16 + r16];

  f32x4 areg[8];
  f32x4 acc[2][4];
  const f32x4 fzero = {0.f, 0.f, 0.f, 0.f};
  #pragma unroll
  for (int m = 0; m < 2; ++m)
    #pragma unroll
    for (int n = 0; n < 4; ++n) acc[m][n] = fzero;

  // prologue: A macro 0 + W sub 0
  #pragma unroll
  for (int j = 0; j < 8; ++j)
    areg[j] = *(const f32x4*)(aptr + j * 32);
  #pragma unroll
  for (int i = 0; i < 8; ++i) {
    const unsigned short* g = wptr + (size_t)i * (32ull * FT_IN) + wkcs * 8;
    __builtin_amdgcn_global_load_lds((gas1_t)g,
        (las3_t)&sW[0][(i * 256 + tid) * 16], 16, 0, 0);
  }

  const int xr  = (arow & 7) << 4;             // sA row XOR (write side)
  const int swz = (r16 & 7) << 4;              // read-side XOR
  int buf = 0;

  for (int mt = 0; mt <= NMACRO; ++mt) {
    const bool lastm = (mt == NMACRO);
    // phase A: cvt + store A(mt). chunk j -> sub j>>1, k-unit (j&1)*8+achk
    if (!lastm) {
      #pragma unroll
      for (int j = 0; j < 8; ++j) {
        f32x4 v = areg[j];
        uint32_t b0, b1;
        CVTPK(b0, v.x, v.y);
        CVTPK(b1, v.z, v.w);
        u32x2 b; b.x = b0; b.y = b1;
        *(u32x2*)(&sA[j >> 1][0] + arow * 128 +
                  ((((j & 1) * 64) + achk * 8) ^ xr)) = b;
      }
    } else {
      #pragma unroll
      for (int j = 0; j < 2; ++j) {            // leftover 64-K -> sub 0
        f32x4 v = areg[j];
        uint32_t b0, b1;
        CVTPK(b0, v.x, v.y);
        CVTPK(b1, v.z, v.w);
        u32x2 b; b.x = b0; b.y = b1;
        *(u32x2*)(&sA[0][0] + arow * 128 + ((j * 64 + achk * 8) ^ xr)) = b;
      }
    }
    const int nsub = lastm ? 1 : 4;
    for (int s2 = 0; s2 < nsub; ++s2) {
      // entry sync: drains W(gs) glds (issued one sub ago); sA visible
      __syncthreads();
      const int gs = mt * 4 + s2;
      if (gs < 640) {                          // stage W(gs+1) into buf^1
        const unsigned short* wp = wptr + (size_t)(gs + 1) * 64;
        #pragma unroll
        for (int i = 0; i < 8; ++i) {
          const unsigned short* g = wp + (size_t)i * (32ull * FT_IN) + wkcs * 8;
          __builtin_amdgcn_global_load_lds((gas1_t)g,
              (las3_t)&sW[buf ^ 1][(i * 256 + tid) * 16], 16, 0, 0);
        }
      }
      if (!lastm && s2 == 3) {                 // prefetch A(mt+1)
        if (mt + 1 < NMACRO) {
          const float* ap = aptr + (size_t)(mt + 1) * 256;
          #pragma unroll
          for (int j = 0; j < 8; ++j)
            areg[j] = *(const f32x4*)(ap + j * 32);
        } else {                               // leftover: j=0..1
          const float* ap = aptr + (size_t)NMACRO * 256;
          areg[0] = *(const f32x4*)(ap);
          areg[1] = *(const f32x4*)(ap + 32);
        }
      }
      // MFMA over sA sub s2 x sW[buf] — proven read pattern
      const char* sAs = &sA[s2][0];
      const char* sWb = sW[buf];
      #pragma unroll
      for (int k2 = 0; k2 < 2; ++k2) {
        const int ko = (k2 * 64 + hi * 16) ^ swz;
        short8 av[2], bv[4];
        #pragma unroll
        for (int m = 0; m < 2; ++m)
          av[m] = *(const short8*)(sAs + (m * 16 + r16) * 128 + ko);
        #pragma unroll
        for (int n = 0; n < 4; ++n)
          bv[n] = *(const short8*)(sWb + (wc + n * 16 + r16) * 128 + ko);
        #pragma unroll
        for (int m = 0; m < 2; ++m)
          #pragma unroll
          for (int n = 0; n < 4; ++n)
            MFMA16(acc[m][n], av[m], bv[n]);
      }
      buf ^= 1;
    }
    // macro end: raw barrier (no vmcnt drain) before sA overwrite
    __builtin_amdgcn_sched_barrier(0);
    __builtin_amdgcn_s_barrier();
    __builtin_amdgcn_sched_barrier(0);
  }

  // epilogue: ft = clip01(acc + ftb), fp16, layout [set*256+col][row]
  _Float16* pb = ftout + (size_t)(st * KHALF) * BATCH;
  const int growb = rb * 32 + hi * 4;
  #pragma unroll
  for (int n = 0; n < 4; ++n) {
    const int gcol = wc + n * 16 + r16;
    #pragma unroll
    for (int m = 0; m < 2; ++m) {
      f32x4 a = acc[m][n];
      half4v h;
      h.x = (_Float16)fminf(fmaxf(a.x + fb[n], 0.f), 1.f);
      h.y = (_Float16)fminf(fmaxf(a.y + fb[n], 0.f), 1.f);
      h.z = (_Float16)fminf(fmaxf(a.z + fb[n], 0.f), 1.f);
      h.w = (_Float16)fminf(fmaxf(a.w + fb[n], 0.f), 1.f);
      *(half4v*)(pb + (size_t)gcol * BATCH + (growb + m * 16)) = h;
    }
  }
}

// ---------------- kernel 3: tail MLP ----------------
// 256 blocks x 32 rows; ft already biased+clipped (fp16, [c][row]).
__global__ __launch_bounds__(256) void tail_kernel(
    const _Float16* __restrict__ ft,
    const float* __restrict__ h1w, const float* __restrict__ h1b,
    const float* __restrict__ h2w, const float* __restrict__ h2b,
    const float* __restrict__ outw, const float* __restrict__ outb,
    float* __restrict__ out) {
  __shared__ float sh1t[512 * 36];
  __shared__ float sh2[32 * 32];
  __shared__ float sow[32];
  __shared__ float sh1b[32];
  __shared__ float sh2b[32];
  __shared__ float sob[1];

  const int tid = (int)threadIdx.x;
  for (int i = tid; i < 512 * 32; i += 256) {
    const int j = i >> 9, c = i & 511;
    sh1t[c * 36 + j] = h1w[i];
  }
  for (int i = tid; i < 1024; i += 256) sh2[i] = h2w[i];
  if (tid < 32) { sow[tid] = outw[tid]; sh1b[tid] = h1b[tid]; sh2b[tid] = h2b[tid]; }
  if (tid == 0) sob[0] = outb[0];
  __syncthreads();

  const int r  = tid & 31;
  const int cg = tid >> 5;
  const int t  = (int)blockIdx.x * 32 + r;

  float a1p[32];
  #pragma unroll
  for (int j = 0; j < 32; ++j) a1p[j] = 0.f;

  for (int ci = 0; ci < 64; ++ci) {
    const int c = cg * 64 + ci;
    float v = (float)ft[(size_t)c * BATCH + t];
    const f32x4* wr4 = (const f32x4*)(sh1t + c * 36);
    #pragma unroll
    for (int q = 0; q < 8; ++q) {
      f32x4 wv = wr4[q];
      a1p[q * 4 + 0] += v * wv.x; a1p[q * 4 + 1] += v * wv.y;
      a1p[q * 4 + 2] += v * wv.z; a1p[q * 4 + 3] += v * wv.w;
    }
  }

  float* red = sh1t;                  // [8][32][33]
  __syncthreads();
  #pragma unroll
  for (int j = 0; j < 32; ++j)
    red[(cg * 32 + r) * 33 + j] = a1p[j];
  __syncthreads();

  if (tid < 32) {
    float a1[32];
    #pragma unroll
    for (int j = 0; j < 32; ++j) a1[j] = sh1b[j];
    for (int g = 0; g < 8; ++g)
      #pragma unroll
      for (int j = 0; j < 32; ++j)
        a1[j] += red[(g * 32 + tid) * 33 + j];
    #pragma unroll
    for (int j = 0; j < 32; ++j) a1[j] = fminf(fmaxf(a1[j], 0.f), 1.f);

    float a2[32];
    #pragma unroll
    for (int j = 0; j < 32; ++j) {
      float x = sh2b[j];
      const f32x4* w2 = (const f32x4*)(sh2 + j * 32);
      #pragma unroll
      for (int q = 0; q < 8; ++q) {
        f32x4 wv = w2[q];
        x += a1[q * 4 + 0] * wv.x + a1[q * 4 + 1] * wv.y +
             a1[q * 4 + 2] * wv.z + a1[q * 4 + 3] * wv.w;
      }
      a2[j] = fminf(fmaxf(x, 0.f), 1.f);
    }
    float o = sob[0];
    #pragma unroll
    for (int j = 0; j < 32; ++j) o += a2[j] * sow[j];
    out[(int)blockIdx.x * 32 + tid] = o;
  }
}

// ---------------- launch ----------------
extern "C" void kernel_launch(void* const* d_in, const int* in_sizes, int n_in,
                              void* d_out, int out_size, void* d_ws, size_t ws_size,
                              hipStream_t stream) {
  const float* f1   = (const float*)d_in[0];
  const float* f2   = (const float*)d_in[1];
  const float* ftw  = (const float*)d_in[2];
  const float* ftb  = (const float*)d_in[3];
  const float* h1w  = (const float*)d_in[4];
  const float* h1b  = (const float*)d_in[5];
  const float* h2w  = (const float*)d_in[6];
  const float* h2b  = (const float*)d_in[7];
  const float* outw = (const float*)d_in[8];
  const float* outb = (const float*)d_in[9];
  float* out = (float*)d_out;

  unsigned short* wb = (unsigned short*)d_ws;
  const size_t woff = (size_t)KHALF * FT_IN * 2;            // 21,004,288 B
  _Float16* ftbuf = (_Float16*)((char*)d_ws + woff);        // 8.4 MB

  wprep_kernel<<<2048, 256, 0, stream>>>(ftw, wb, (KHALF * FT_IN) / 4);
  ftgemm_kernel<<<512, 256, 0, stream>>>(f1, f2, wb, ftb, ftbuf);
  tail_kernel<<<BATCH / 32, 256, 0, stream>>>(ftbuf, h1w, h1b, h2w, h2b,
                                              outw, outb, out);
}

// Round 17
// 654.801 us; speedup vs baseline: 1.8055x; 1.7144x over previous
//
#include <hip/hip_runtime.h>
#include <stdint.h>
#include <stddef.h>

#define FT_IN 41024
#define KHALF 256
#define BATCH 8192
#define NKT 641          // 41024 / 64 K-tiles

typedef __attribute__((ext_vector_type(8))) short short8;
typedef __attribute__((ext_vector_type(4))) short short4v;
typedef __attribute__((ext_vector_type(4))) float f32x4;
typedef __attribute__((ext_vector_type(2))) uint32_t u32x2;
typedef __attribute__((ext_vector_type(4))) _Float16 half4v;

typedef const __attribute__((address_space(1))) uint32_t* gas1_t;
typedef __attribute__((address_space(3))) uint32_t* las3_t;

// fp32 -> bf16 RNE (bit trick) — used only in the small wprep pass
__device__ __forceinline__ unsigned short f2bf(float f) {
  union { float f; uint32_t u; } x; x.f = f;
  uint32_t u = x.u + 0x7FFFu + ((x.u >> 16) & 1u);
  return (unsigned short)(u >> 16);
}

#define MFMA16(acc, a, b) \
  asm("v_mfma_f32_16x16x32_bf16 %0, %1, %2, %0" : "+v"(acc) : "v"(a), "v"(b))

// packed fp32x2 -> bf16x2 (RNE), lo -> bits[15:0]
#define CVTPK(dst, lo, hi) \
  asm("v_cvt_pk_bf16_f32 %0, %1, %2" : "=v"(dst) : "v"(lo), "v"(hi))

// ---------------- kernel 1: ft_w fp32 -> bf16 ----------------
__global__ void wprep_kernel(const float* __restrict__ w,
                             unsigned short* __restrict__ o, int n4) {
  int i = blockIdx.x * blockDim.x + threadIdx.x;
  int stride = gridDim.x * blockDim.x;
  for (; i < n4; i += stride) {
    f32x4 v = ((const f32x4*)w)[i];
    short4v b;
    b.x = (short)f2bf(v.x); b.y = (short)f2bf(v.y);
    b.z = (short)f2bf(v.z); b.w = (short)f2bf(v.w);
    ((short4v*)o)[i] = b;
  }
}

// ---------------- kernel 2: feature-transform GEMM ----------------
// (R14 = R4 structure + fp16 partials, proven 653 us / absmax 2.44e-4.
//  This round: ONLY adds non-temporal hints — A loads (zero reuse, keep
//  them from evicting W's L2 window) and partial stores (streamed once).)
// grid: 64 rowblocks x 2 sets x KS kchunks (512 WGs = 2/CU); block 256.
// per-WG tile: 128 rows x 256 cols (features read ONCE), BK=64.
// A: fp32 global (nt) -> v_cvt_pk_bf16 -> LDS (XOR-swizzled). W: bf16 ->
// global_load_lds (source pre-swizzled), double-buffered (2x32KB).
// barrier1 = __syncthreads (drains 1-iteration-old W glds, ~free);
// barrier2 = raw s_barrier (A(t+1)/W(t+1) prefetch stays in flight).
__global__ __launch_bounds__(256, 2) void ftgemm_kernel(
    const float* __restrict__ f1g, const float* __restrict__ f2g,
    const unsigned short* __restrict__ wb,
    _Float16* __restrict__ part, int KS) {
  __shared__ alignas(16) char sA[16384];
  __shared__ alignas(16) char sW[2][32768];

  // XCD-aware chunked swizzle (nwg = 128*KS, divisible by 8 for KS in {1,2,4})
  const int nwg = (int)gridDim.x;
  const int orig = (int)blockIdx.x;
  int bid = (orig & 7) * (nwg >> 3) + (orig >> 3);

  const int rb = bid & 63; bid >>= 6;
  const int st = bid & 1;  bid >>= 1;
  const int ks = bid;

  const int kt0 = (ks * NKT) / KS;
  const int kt1 = ((ks + 1) * NKT) / KS;

  const int tid  = (int)threadIdx.x;
  const int lane = tid & 63;
  const int wv   = tid >> 6;
  const int wr   = (wv >> 1) << 6;   // wave row offset: 0 / 64
  const int wc   = (wv & 1) << 7;    // wave col offset: 0 / 128
  const int r16  = lane & 15;
  const int hi   = lane >> 4;

  const float* F = (st ? f2g : f1g) + (size_t)rb * (128ull * FT_IN);

  // A staging: thread covers rows (i*16 + tid>>4), k-chunk (tid&15)*4 floats
  const int arow = tid >> 4;
  const int akc  = tid & 15;
  const float* aptr = F + (size_t)arow * FT_IN + (size_t)kt0 * 64 + akc * 4;

  // W staging (global_load_lds, linear LDS dest): chunk c = i*256+tid,
  // row = c>>3 (i adds 32 rows), kc = c&7; source XOR-pre-swizzled.
  const int wrow = tid >> 3;
  const int wkc  = tid & 7;
  const int wkcs = wkc ^ (wrow & 7);
  const unsigned short* wptr =
      wb + (size_t)wrow * FT_IN + (size_t)kt0 * 64;

  f32x4 areg[8];
  f32x4 acc[4][8];
  const f32x4 fzero = {0.f, 0.f, 0.f, 0.f};
  #pragma unroll
  for (int m = 0; m < 4; ++m)
    #pragma unroll
    for (int n = 0; n < 8; ++n) acc[m][n] = fzero;

  // prologue: A regs (nt) + W glds for tile kt0
  #pragma unroll
  for (int i = 0; i < 8; ++i)
    areg[i] = __builtin_nontemporal_load(
        (const f32x4*)(aptr + (size_t)i * (16ull * FT_IN)));
  #pragma unroll
  for (int i = 0; i < 8; ++i) {
    const unsigned short* g = wptr + (size_t)i * (32ull * FT_IN) + wkcs * 8;
    __builtin_amdgcn_global_load_lds((gas1_t)g,
        (las3_t)&sW[0][(i * 256 + tid) * 16], 16, 0, 0);
  }

  int buf = 0;
  for (int kt = kt0; kt < kt1; ++kt) {
    // phase A: cvt + store A tile (swizzle: byte ^= (row&7)<<4)
    #pragma unroll
    for (int i = 0; i < 8; ++i) {
      const int row = i * 16 + arow;
      f32x4 v = areg[i];
      uint32_t b0, b1;
      CVTPK(b0, v.x, v.y);
      CVTPK(b1, v.z, v.w);
      u32x2 b; b.x = b0; b.y = b1;
      *(u32x2*)(sA + row * 128 + ((akc * 8) ^ ((row & 7) << 4))) = b;
    }
    // barrier 1: full drain — only W(t) (issued one iteration ago) is
    // outstanding, so the vmcnt(0) is nearly free. sA(t)+sW[buf] visible.
    __syncthreads();

    // phase B: issue next tile's loads (stay in flight across barrier 2)
    if (kt + 1 < kt1) {
      const int d = kt + 1 - kt0;
      const float* ap = aptr + d * 64;
      #pragma unroll
      for (int i = 0; i < 8; ++i)
        areg[i] = __builtin_nontemporal_load(
            (const f32x4*)(ap + (size_t)i * (16ull * FT_IN)));
      const unsigned short* wp = wptr + d * 64;
      #pragma unroll
      for (int i = 0; i < 8; ++i) {
        const unsigned short* g = wp + (size_t)i * (32ull * FT_IN) + wkcs * 8;
        __builtin_amdgcn_global_load_lds((gas1_t)g,
            (las3_t)&sW[buf ^ 1][(i * 256 + tid) * 16], 16, 0, 0);
      }
    }

    // phase C: MFMA
    const char* sWb = sW[buf];
    const int swz = (r16 & 7) << 4;
    #pragma unroll
    for (int k2 = 0; k2 < 2; ++k2) {
      const int ko = (k2 * 64 + hi * 16) ^ swz;
      short8 av[4], bv[8];
      #pragma unroll
      for (int m = 0; m < 4; ++m)
        av[m] = *(const short8*)(sA + (wr + m * 16 + r16) * 128 + ko);
      #pragma unroll
      for (int n = 0; n < 8; ++n)
        bv[n] = *(const short8*)(sWb + (wc + n * 16 + r16) * 128 + ko);
      #pragma unroll
      for (int m = 0; m < 4; ++m)
        #pragma unroll
        for (int n = 0; n < 8; ++n)
          MFMA16(acc[m][n], av[m], bv[n]);
    }

    // barrier 2: RAW s_barrier — no vmcnt drain; A(t+1)/W(t+1) stay in
    // flight through the next cvt phase (double-buffered sW -> no race).
    __builtin_amdgcn_sched_barrier(0);
    __builtin_amdgcn_s_barrier();
    __builtin_amdgcn_sched_barrier(0);
    buf ^= 1;
  }

  // epilogue: fp16 partials [ks*2+set][col][row], nt stores (write-once,
  // consumed by tail kernel much later — keep out of L2).
  _Float16* pb = part + (size_t)(ks * 2 + st) * (KHALF * (size_t)BATCH);
  const int growb = rb * 128 + wr + hi * 4;
  const int gcolb = wc + r16;
  #pragma unroll
  for (int n = 0; n < 8; ++n)
    #pragma unroll
    for (int m = 0; m < 4; ++m) {
      f32x4 a = acc[m][n];
      half4v h;
      h.x = (_Float16)a.x; h.y = (_Float16)a.y;
      h.z = (_Float16)a.z; h.w = (_Float16)a.w;
      __builtin_nontemporal_store(h,
          (half4v*)(pb + (size_t)(gcolb + n * 16) * BATCH + (growb + m * 16)));
    }
}

// ---------------- kernel 3: tail MLP ----------------
// 256 blocks x 32 rows. Thread (r = tid&31, cg = tid>>5): row r, 64 cols
// [cg*64, cg*64+64). a1-partials reduced across the 8 col-groups via LDS.
__global__ __launch_bounds__(256) void tail_kernel(
    const _Float16* __restrict__ part,
    const float* __restrict__ ftb, const float* __restrict__ h1w,
    const float* __restrict__ h1b, const float* __restrict__ h2w,
    const float* __restrict__ h2b, const float* __restrict__ outw,
    const float* __restrict__ outb, float* __restrict__ out, int KS) {
  __shared__ float sh1t[512 * 36];   // h1_w transposed [c][j], stride 36 (pad)
  __shared__ float sh2[32 * 32];
  __shared__ float sow[32];
  __shared__ float sh1b[32];
  __shared__ float sh2b[32];
  __shared__ float sftb[256];
  __shared__ float sob[1];

  const int tid = (int)threadIdx.x;
  // coalesced global read (c fast), strided LDS write
  for (int i = tid; i < 512 * 32; i += 256) {
    const int j = i >> 9, c = i & 511;
    sh1t[c * 36 + j] = h1w[i];       // h1w[j][c]
  }
  for (int i = tid; i < 1024; i += 256) sh2[i] = h2w[i];
  if (tid < 32) { sow[tid] = outw[tid]; sh1b[tid] = h1b[tid]; sh2b[tid] = h2b[tid]; }
  sftb[tid] = ftb[tid];
  if (tid == 0) sob[0] = outb[0];
  __syncthreads();

  const int r  = tid & 31;
  const int cg = tid >> 5;
  const int t  = (int)blockIdx.x * 32 + r;   // global batch row

  float a1p[32];
  #pragma unroll
  for (int j = 0; j < 32; ++j) a1p[j] = 0.f;

  for (int ci = 0; ci < 64; ++ci) {
    const int c   = cg * 64 + ci;
    const int set = c >> 8;
    const int cs  = c & 255;
    float v = sftb[cs];
    const _Float16* p = part + ((size_t)set * KHALF + cs) * BATCH + t;
    for (int kq = 0; kq < KS; ++kq)
      v += (float)p[(size_t)kq * (2ull * KHALF * BATCH)];
    v = fminf(fmaxf(v, 0.f), 1.f);
    const f32x4* wr4 = (const f32x4*)(sh1t + c * 36);
    #pragma unroll
    for (int q = 0; q < 8; ++q) {
      f32x4 wv = wr4[q];
      a1p[q * 4 + 0] += v * wv.x; a1p[q * 4 + 1] += v * wv.y;
      a1p[q * 4 + 2] += v * wv.z; a1p[q * 4 + 3] += v * wv.w;
    }
  }

  // reduce the 8 col-group partials per row via LDS (reuse sh1t region)
  float* red = sh1t;                  // [8][32][33]
  __syncthreads();
  #pragma unroll
  for (int j = 0; j < 32; ++j)
    red[(cg * 32 + r) * 33 + j] = a1p[j];
  __syncthreads();

  if (tid < 32) {
    float a1[32];
    #pragma unroll
    for (int j = 0; j < 32; ++j) a1[j] = sh1b[j];
    for (int g = 0; g < 8; ++g)
      #pragma unroll
      for (int j = 0; j < 32; ++j)
        a1[j] += red[(g * 32 + tid) * 33 + j];
    #pragma unroll
    for (int j = 0; j < 32; ++j) a1[j] = fminf(fmaxf(a1[j], 0.f), 1.f);

    float a2[32];
    #pragma unroll
    for (int j = 0; j < 32; ++j) {
      float x = sh2b[j];
      const f32x4* w2 = (const f32x4*)(sh2 + j * 32);
      #pragma unroll
      for (int q = 0; q < 8; ++q) {
        f32x4 wv = w2[q];
        x += a1[q * 4 + 0] * wv.x + a1[q * 4 + 1] * wv.y +
             a1[q * 4 + 2] * wv.z + a1[q * 4 + 3] * wv.w;
      }
      a2[j] = fminf(fmaxf(x, 0.f), 1.f);
    }
    float o = sob[0];
    #pragma unroll
    for (int j = 0; j < 32; ++j) o += a2[j] * sow[j];
    out[(int)blockIdx.x * 32 + tid] = o;
  }
}

// ---------------- launch ----------------
extern "C" void kernel_launch(void* const* d_in, const int* in_sizes, int n_in,
                              void* d_out, int out_size, void* d_ws, size_t ws_size,
                              hipStream_t stream) {
  const float* f1   = (const float*)d_in[0];
  const float* f2   = (const float*)d_in[1];
  const float* ftw  = (const float*)d_in[2];
  const float* ftb  = (const float*)d_in[3];
  const float* h1w  = (const float*)d_in[4];
  const float* h1b  = (const float*)d_in[5];
  const float* h2w  = (const float*)d_in[6];
  const float* h2b  = (const float*)d_in[7];
  const float* outw = (const float*)d_in[8];
  const float* outb = (const float*)d_in[9];
  float* out = (float*)d_out;

  unsigned short* wb = (unsigned short*)d_ws;
  const size_t woff = (size_t)KHALF * FT_IN * 2;            // 21,004,288 B
  _Float16* part = (_Float16*)((char*)d_ws + woff);
  const size_t per = 2ull * KHALF * BATCH * 2;              // 8,388,608 B / kchunk

  // KS=4 -> 64rb x 2set x 4 = 512 WGs = exactly 2 WGs/CU (80 KB LDS), 1 round
  int KS = 1;
  if (ws_size >= woff + 4 * per)      KS = 4;
  else if (ws_size >= woff + 2 * per) KS = 2;

  wprep_kernel<<<2048, 256, 0, stream>>>(ftw, wb, (KHALF * FT_IN) / 4);
  ftgemm_kernel<<<dim3(64 * 2 * KS), 256, 0, stream>>>(f1, f2, wb, part, KS);
  tail_kernel<<<BATCH / 32, 256, 0, stream>>>(part, ftb, h1w, h1b, h2w, h2b,
                                              outw, outb, out, KS);
}